// Round 2
// baseline (10433.303 us; speedup 1.0000x reference)
//
#include <hip/hip_runtime.h>
#include <math.h>

typedef __bf16 bf16;
typedef __attribute__((ext_vector_type(8))) __bf16 bf16x8;
typedef __attribute__((ext_vector_type(4))) float f32x4;

// Model constants
#define NB    2
#define TT    8
#define NP    196
#define CC    768
#define NH    12
#define SEQ   1569      // 1 + TT*NP
#define MT_R  3136      // (NB*NP)*TT  temporal rows
#define MS_R  3152      // (NB*TT)*197 spatial rows
#define MM_R  3138      // NB*SEQ      mlp rows

enum { MODE_BF16 = 0, MODE_GELU = 1, MODE_EMBED = 2, MODE_TADD = 3, MODE_SADD = 4, MODE_MADD = 5 };

// ---------------------------------------------------------------------------
// Generic GEMM: C = A(MxK,bf16) * W^T (W: NxK,fp32 -> bf16 on the fly) + bias.
// 256 threads = 4 waves (2x2); each wave: 64 x (16*NT) via 4xNT mfma 16x16x32.
// ---------------------------------------------------------------------------
template<int NT>
__global__ __launch_bounds__(256, 2)
void gemm_kernel(const bf16* __restrict__ A, int M, int K,
                 const float* __restrict__ W, int N,
                 const float* __restrict__ bias, int mode,
                 bf16* __restrict__ outb, float* __restrict__ X,
                 const float* __restrict__ aux0, const float* __restrict__ aux1)
{
    constexpr int BN = 32 * NT;                  // 128 or 64
    __shared__ bf16 sA[128 * 32];
    __shared__ bf16 sB[BN * 32];
    const int tid  = threadIdx.x;
    const int lane = tid & 63;
    const int w    = tid >> 6;
    const int wr   = w >> 1, wc = w & 1;
    const int l15  = lane & 15, l4 = lane >> 4;
    const int m0   = blockIdx.x * 128;
    const int n0   = blockIdx.y * BN;

    f32x4 acc[4][NT];
#pragma unroll
    for (int mt = 0; mt < 4; ++mt)
#pragma unroll
        for (int nt = 0; nt < NT; ++nt) acc[mt][nt] = (f32x4){0.f, 0.f, 0.f, 0.f};

    const int nk = K >> 5;
    for (int kt = 0; kt < nk; ++kt) {
        const int k0 = kt * 32;
        uint4 va[2];
#pragma unroll
        for (int i = 0; i < 2; ++i) {
            int idx = i * 256 + tid;
            int row = idx >> 2, ch = idx & 3;
            int gm = m0 + row; if (gm > M - 1) gm = M - 1;
            va[i] = *(const uint4*)(A + (size_t)gm * K + k0 + ch * 8);
        }
        float4 wb0[NT / 2], wb1[NT / 2];
#pragma unroll
        for (int i = 0; i < NT / 2; ++i) {
            int idx = i * 256 + tid;
            int row = idx >> 2, ch = idx & 3;
            const float* wp = W + (size_t)(n0 + row) * K + k0 + ch * 8;
            wb0[i] = *(const float4*)(wp);
            wb1[i] = *(const float4*)(wp + 4);
        }
#pragma unroll
        for (int i = 0; i < 2; ++i)      { int idx = i * 256 + tid; *(uint4*)(sA + idx * 8) = va[i]; }
#pragma unroll
        for (int i = 0; i < NT / 2; ++i) {
            int idx = i * 256 + tid;
            union { uint4 u; bf16 e[8]; } cv;
            cv.e[0] = (bf16)wb0[i].x; cv.e[1] = (bf16)wb0[i].y;
            cv.e[2] = (bf16)wb0[i].z; cv.e[3] = (bf16)wb0[i].w;
            cv.e[4] = (bf16)wb1[i].x; cv.e[5] = (bf16)wb1[i].y;
            cv.e[6] = (bf16)wb1[i].z; cv.e[7] = (bf16)wb1[i].w;
            *(uint4*)(sB + idx * 8) = cv.u;
        }
        __syncthreads();

        bf16x8 af[4], bfr[NT];
#pragma unroll
        for (int mt = 0; mt < 4; ++mt)
            af[mt] = *(const bf16x8*)(sA + (wr * 64 + mt * 16 + l15) * 32 + l4 * 8);
#pragma unroll
        for (int nt = 0; nt < NT; ++nt)
            bfr[nt] = *(const bf16x8*)(sB + (wc * 16 * NT + nt * 16 + l15) * 32 + l4 * 8);
#pragma unroll
        for (int mt = 0; mt < 4; ++mt)
#pragma unroll
            for (int nt = 0; nt < NT; ++nt)
                acc[mt][nt] = __builtin_amdgcn_mfma_f32_16x16x32_bf16(af[mt], bfr[nt], acc[mt][nt], 0, 0, 0);
        __syncthreads();
    }

    // Epilogue. C/D layout: col = lane&15, row = (lane>>4)*4 + reg.
#pragma unroll
    for (int nt = 0; nt < NT; ++nt) {
        const int gn = n0 + wc * 16 * NT + nt * 16 + l15;
        const float bv = bias[gn];
#pragma unroll
        for (int mt = 0; mt < 4; ++mt) {
#pragma unroll
            for (int r = 0; r < 4; ++r) {
                const int gm = m0 + wr * 64 + mt * 16 + l4 * 4 + r;
                if (gm >= M) continue;
                float v = acc[mt][nt][r] + bv;
                if (mode == MODE_BF16) {
                    outb[(size_t)gm * N + gn] = (bf16)v;
                } else if (mode == MODE_GELU) {
                    v = 0.5f * v * (1.f + erff(v * 0.70710678118f));
                    outb[(size_t)gm * N + gn] = (bf16)v;
                } else if (mode == MODE_EMBED) {
                    // m = (b*8+t)*196 + n ; X[b,1+t*196+n] = v + pos[1+n] + time[t]
                    int bt = gm / 196, n = gm - bt * 196;
                    int b = bt >> 3, t = bt & 7;
                    v += aux0[(1 + n) * CC + gn] + aux1[t * CC + gn];
                    X[((size_t)b * SEQ + 1 + t * 196 + n) * CC + gn] = v;
                } else if (mode == MODE_TADD) {
                    // m = (b*196+n)*8 + t ; X[b,1+t*196+n] += v
                    int bn = gm >> 3, t = gm & 7;
                    int b = bn / 196, n = bn - b * 196;
                    X[((size_t)b * SEQ + 1 + t * 196 + n) * CC + gn] += v;
                } else if (mode == MODE_SADD) {
                    // m = (b*8+t)*197 + j
                    int bt = gm / 197, j = gm - bt * 197;
                    int b = bt >> 3, t = bt & 7;
                    if (j == 0) atomicAdd(&X[(size_t)b * SEQ * CC + gn], v * 0.125f);
                    else        X[((size_t)b * SEQ + 1 + t * 196 + (j - 1)) * CC + gn] += v;
                } else { // MODE_MADD: m = b*SEQ + s
                    X[(size_t)gm * CC + gn] += v;
                }
            }
        }
    }
}

// ---------------------------------------------------------------------------
// LayerNorm: one wave per row, fp32 in -> bf16 out, with row remapping.
// mode 0: temporal (b,n,t); 1: spatial (b,t,j) incl cls; 2: identity; 3: final cls
// ---------------------------------------------------------------------------
__global__ __launch_bounds__(256)
void ln_kernel(const float* __restrict__ X, bf16* __restrict__ out,
               const float* __restrict__ w, const float* __restrict__ b,
               int rows, int mode)
{
    const int row = blockIdx.x * 4 + (threadIdx.x >> 6);
    if (row >= rows) return;
    const int lane = threadIdx.x & 63;
    size_t xr;
    if (mode == 0) {
        int bb = row / 1568, rem = row - bb * 1568;
        int n = rem >> 3, t = rem & 7;
        xr = (size_t)bb * SEQ + 1 + t * 196 + n;
    } else if (mode == 1) {
        int bt = row / 197, j = row - bt * 197;
        int bb = bt >> 3, t = bt & 7;
        xr = (j == 0) ? (size_t)bb * SEQ : ((size_t)bb * SEQ + 1 + t * 196 + (j - 1));
    } else if (mode == 2) {
        xr = (size_t)row;
    } else {
        xr = (size_t)row * SEQ;
    }
    const float* xp = X + xr * CC;
    float v[12], s = 0.f, ss = 0.f;
#pragma unroll
    for (int i = 0; i < 12; ++i) { float t = xp[lane + 64 * i]; v[i] = t; s += t; ss += t * t; }
#pragma unroll
    for (int d = 1; d < 64; d <<= 1) { s += __shfl_xor(s, d, 64); ss += __shfl_xor(ss, d, 64); }
    const float mean = s * (1.f / 768.f);
    const float var  = ss * (1.f / 768.f) - mean * mean;
    const float rstd = rsqrtf(var + 1e-6f);
    bf16* op = out + (size_t)row * CC;
#pragma unroll
    for (int i = 0; i < 12; ++i) {
        int c = lane + 64 * i;
        op[c] = (bf16)((v[i] - mean) * rstd * w[c] + b[c]);
    }
}

// ---------------------------------------------------------------------------
// Temporal attention: seq=8, one wave per (b,n,head). QKV rows ordered (b,n,t).
// ---------------------------------------------------------------------------
__global__ __launch_bounds__(256)
void attn_t_kernel(const bf16* __restrict__ QKV, bf16* __restrict__ O)
{
    const int unit = blockIdx.x * 4 + (threadIdx.x >> 6);   // 0..4703
    const int lane = threadIdx.x & 63;
    const int bn = unit / 12, h = unit - bn * 12;
    const size_t base = (size_t)bn * 8 * 2304;
    const int qi = lane >> 3, qj = lane & 7;
    const bf16x8* q8 = (const bf16x8*)(QKV + base + (size_t)qi * 2304 + h * 64);
    const bf16x8* k8 = (const bf16x8*)(QKV + base + (size_t)qj * 2304 + 768 + h * 64);
    float s = 0.f;
#pragma unroll
    for (int c = 0; c < 8; ++c) {
        bf16x8 qa = q8[c], kb = k8[c];
#pragma unroll
        for (int e = 0; e < 8; ++e) s += (float)qa[e] * (float)kb[e];
    }
    s *= 0.125f;
    float mx = s;
    mx = fmaxf(mx, __shfl_xor(mx, 1, 8));
    mx = fmaxf(mx, __shfl_xor(mx, 2, 8));
    mx = fmaxf(mx, __shfl_xor(mx, 4, 8));
    float p = __expf(s - mx);
    float sum = p;
    sum += __shfl_xor(sum, 1, 8);
    sum += __shfl_xor(sum, 2, 8);
    sum += __shfl_xor(sum, 4, 8);
    p /= sum;
    float o[8];
#pragma unroll
    for (int e = 0; e < 8; ++e) o[e] = 0.f;
#pragma unroll
    for (int jj = 0; jj < 8; ++jj) {
        float pj = __shfl(p, (qi << 3) + jj, 64);
        bf16x8 vv = *(const bf16x8*)(QKV + base + (size_t)jj * 2304 + 1536 + h * 64 + qj * 8);
#pragma unroll
        for (int e = 0; e < 8; ++e) o[e] += pj * (float)vv[e];
    }
    bf16* op = O + (size_t)(bn * 8 + qi) * CC + h * 64 + qj * 8;
#pragma unroll
    for (int e = 0; e < 8; ++e) op[e] = (bf16)o[e];
}

// ---------------------------------------------------------------------------
// Spatial attention: seq=197, one block (4 waves) per (b,t,head) = 192 units.
// MFMA QK^T -> LDS softmax -> MFMA PV. K/V frags hoisted to registers.
// ---------------------------------------------------------------------------
__global__ __launch_bounds__(256)
void attn_s_kernel(const bf16* __restrict__ QKV, bf16* __restrict__ O)
{
    const int unit = blockIdx.x;                 // 0..191
    const int bt = unit / 12, h = unit - bt * 12;
    const int lane = threadIdx.x & 63;
    const int w = threadIdx.x >> 6;
    const size_t ubase = (size_t)bt * 197;
    const int qo = h * 64, ko = 768 + h * 64, vo = 1536 + h * 64;
    const int l15 = lane & 15, l4 = lane >> 4;

    __shared__ float S[16][208];
    __shared__ bf16  P[16][224];

    // zero P pad columns (197..223) once; never rewritten
    for (int idx = threadIdx.x; idx < 16 * 27; idx += 256)
        P[idx / 27][197 + (idx % 27)] = (bf16)0.f;

    // Hoisted K fragments: wave w owns n-tiles {w, w+4, w+8, (w+12)}
    const int nnt = (w == 0) ? 4 : 3;
    bf16x8 kf[4][2];
    int ntv[4];
    for (int i = 0; i < nnt; ++i) {
        int nt = w + 4 * i; ntv[i] = nt;
        int j = nt * 16 + l15; if (j > 196) j = 196;
        const bf16* kp = QKV + (ubase + j) * 2304 + ko + l4 * 8;
        kf[i][0] = *(const bf16x8*)(kp);
        kf[i][1] = *(const bf16x8*)(kp + 32);
    }
    // Hoisted V fragments for PV (wave w owns d-tile w): B[k=j][n=d]
    bf16x8 vf[7];
    for (int kt = 0; kt < 7; ++kt) {
        union { bf16x8 v; __bf16 e[8]; } u;
#pragma unroll
        for (int jj = 0; jj < 8; ++jj) {
            int j = kt * 32 + l4 * 8 + jj; if (j > 196) j = 196;
            u.e[jj] = QKV[(ubase + j) * 2304 + vo + w * 16 + l15];
        }
        vf[kt] = u.v;
    }
    __syncthreads();

    for (int mc = 0; mc < 13; ++mc) {
        // Q fragments for this 16-row chunk
        int qm = mc * 16 + l15; if (qm > 196) qm = 196;
        const bf16* qp = QKV + (ubase + qm) * 2304 + qo + l4 * 8;
        bf16x8 qf0 = *(const bf16x8*)(qp);
        bf16x8 qf1 = *(const bf16x8*)(qp + 32);
        // scores -> S
        for (int i = 0; i < nnt; ++i) {
            f32x4 acc = (f32x4){0.f, 0.f, 0.f, 0.f};
            acc = __builtin_amdgcn_mfma_f32_16x16x32_bf16(qf0, kf[i][0], acc, 0, 0, 0);
            acc = __builtin_amdgcn_mfma_f32_16x16x32_bf16(qf1, kf[i][1], acc, 0, 0, 0);
            int col = ntv[i] * 16 + l15;
#pragma unroll
            for (int r = 0; r < 4; ++r) S[l4 * 4 + r][col] = acc[r] * 0.125f;
        }
        __syncthreads();
        // softmax: thread (r = tid>>4) scans cols (tid&15) + 16k, k<13
        {
            const int r = threadIdx.x >> 4, c0 = threadIdx.x & 15;
            float sv[13], mx = -1e30f;
#pragma unroll
            for (int kx = 0; kx < 13; ++kx) {
                int jj = c0 + (kx << 4);
                float t = (jj < 197) ? S[r][jj] : -1e30f;
                sv[kx] = t; mx = fmaxf(mx, t);
            }
#pragma unroll
            for (int d = 1; d < 16; d <<= 1) mx = fmaxf(mx, __shfl_xor(mx, d, 16));
            float sum = 0.f;
#pragma unroll
            for (int kx = 0; kx < 13; ++kx) {
                int jj = c0 + (kx << 4);
                float p = (jj < 197) ? __expf(sv[kx] - mx) : 0.f;
                sv[kx] = p; sum += p;
            }
#pragma unroll
            for (int d = 1; d < 16; d <<= 1) sum += __shfl_xor(sum, d, 16);
            const float inv = 1.f / sum;
#pragma unroll
            for (int kx = 0; kx < 13; ++kx) {
                int jj = c0 + (kx << 4);
                if (jj < 197) P[r][jj] = (bf16)(sv[kx] * inv);
            }
        }
        __syncthreads();
        // PV: wave w computes O[mc*16..+16][w*16..+16]
        f32x4 oacc = (f32x4){0.f, 0.f, 0.f, 0.f};
#pragma unroll
        for (int kt = 0; kt < 7; ++kt) {
            bf16x8 pf = *(const bf16x8*)(&P[l15][kt * 32 + l4 * 8]);
            oacc = __builtin_amdgcn_mfma_f32_16x16x32_bf16(pf, vf[kt], oacc, 0, 0, 0);
        }
#pragma unroll
        for (int r = 0; r < 4; ++r) {
            int m = mc * 16 + l4 * 4 + r;
            if (m < 197) O[(ubase + m) * CC + h * 64 + w * 16 + l15] = (bf16)oacc[r];
        }
        __syncthreads();
    }
}

// ---------------------------------------------------------------------------
__global__ void init_cls_kernel(float* __restrict__ X,
                                const float* __restrict__ cls_tok,
                                const float* __restrict__ pos_emb)
{
    int i = blockIdx.x * 256 + threadIdx.x;
    if (i < 2 * CC) {
        int b = i / CC, c = i - b * CC;
        X[(size_t)b * SEQ * CC + c] = cls_tok[c] + pos_emb[c];
    }
}

__global__ void patch_gather_kernel(const float* __restrict__ x, bf16* __restrict__ A)
{
    size_t idx = (size_t)blockIdx.x * 256 + threadIdx.x;
    if (idx >= (size_t)MT_R * CC) return;
    int col = (int)(idx % CC);
    int m   = (int)(idx / CC);
    int pw = col & 15, ph = (col >> 4) & 15, ci = col >> 8;
    int n = m % 196, bt = m / 196;
    int b = bt >> 3, t = bt & 7;
    int nh = n / 14, nw = n - nh * 14;
    size_t src = ((((size_t)(b * 3 + ci) * 8 + t) * 224) + nh * 16 + ph) * 224 + nw * 16 + pw;
    A[idx] = (bf16)x[src];
}

__global__ __launch_bounds__(256)
void head_kernel(const bf16* __restrict__ A, const float* __restrict__ W,
                 const float* __restrict__ bias, float* __restrict__ out)
{
    __shared__ float a[CC];
    const int b = blockIdx.x;
    for (int i = threadIdx.x; i < CC; i += 256) a[i] = (float)A[b * CC + i];
    __syncthreads();
    if (threadIdx.x >= 250) return;
    const int o = blockIdx.y * 250 + threadIdx.x;
    const float4* wr = (const float4*)(W + (size_t)o * CC);
    float s = 0.f;
    for (int c = 0; c < 192; ++c) {
        float4 wv = wr[c];
        s += a[c * 4 + 0] * wv.x + a[c * 4 + 1] * wv.y + a[c * 4 + 2] * wv.z + a[c * 4 + 3] * wv.w;
    }
    out[b * 1000 + o] = s + bias[o];
}

// ---------------------------------------------------------------------------
extern "C" void kernel_launch(void* const* d_in, const int* in_sizes, int n_in,
                              void* d_out, int out_size, void* d_ws, size_t ws_size,
                              hipStream_t stream)
{
    const float* x        = (const float*)d_in[0];
    const float* conv_w   = (const float*)d_in[1];
    const float* conv_b   = (const float*)d_in[2];
    const float* cls_tok  = (const float*)d_in[3];
    const float* pos_emb  = (const float*)d_in[4];
    const float* time_emb = (const float*)d_in[5];
    const float* tn_w   = (const float*)d_in[6];
    const float* tn_b   = (const float*)d_in[7];
    const float* tqkv_w = (const float*)d_in[8];
    const float* tqkv_b = (const float*)d_in[9];
    const float* tproj_w= (const float*)d_in[10];
    const float* tproj_b= (const float*)d_in[11];
    const float* tfc_w  = (const float*)d_in[12];
    const float* tfc_b  = (const float*)d_in[13];
    const float* n1_w   = (const float*)d_in[14];
    const float* n1_b   = (const float*)d_in[15];
    const float* sqkv_w = (const float*)d_in[16];
    const float* sqkv_b = (const float*)d_in[17];
    const float* sproj_w= (const float*)d_in[18];
    const float* sproj_b= (const float*)d_in[19];
    const float* n2_w   = (const float*)d_in[20];
    const float* n2_b   = (const float*)d_in[21];
    const float* fc1_w  = (const float*)d_in[22];
    const float* fc1_b  = (const float*)d_in[23];
    const float* fc2_w  = (const float*)d_in[24];
    const float* fc2_b  = (const float*)d_in[25];
    const float* norm_w = (const float*)d_in[26];
    const float* norm_b = (const float*)d_in[27];
    const float* head_w = (const float*)d_in[28];
    const float* head_b = (const float*)d_in[29];

    char* ws = (char*)d_ws;
    float* X   = (float*)(ws);                          // 9.2 MiB
    bf16*  Ab  = (bf16*)(ws + ((size_t)10 << 20));      // <=3152x768
    bf16*  QKVb= (bf16*)(ws + ((size_t)15 << 20));      // <=3152x2304
    bf16*  Ob  = (bf16*)(ws + ((size_t)30 << 20));      // <=3152x768
    bf16*  Pb  = (bf16*)(ws + ((size_t)35 << 20));      // 3136x768
    bf16*  Hb  = (bf16*)(ws + ((size_t)40 << 20));      // 3138x3072

    // embed
    init_cls_kernel<<<6, 256, 0, stream>>>(X, cls_tok, pos_emb);
    patch_gather_kernel<<<(MT_R * CC + 255) / 256, 256, 0, stream>>>(x, Ab);
    gemm_kernel<2><<<dim3(25, 12), 256, 0, stream>>>(Ab, MT_R, 768, conv_w, 768, conv_b,
                                                     MODE_EMBED, nullptr, X, pos_emb, time_emb);

    for (int l = 0; l < 12; ++l) {
        const size_t wqkv = (size_t)l * 2304 * 768;
        const size_t wsq  = (size_t)l * 768 * 768;
        const size_t wfc  = (size_t)l * 3072 * 768;
        // temporal
        ln_kernel<<<784, 256, 0, stream>>>(X, Ab, tn_w + l * 768, tn_b + l * 768, MT_R, 0);
        gemm_kernel<4><<<dim3(25, 18), 256, 0, stream>>>(Ab, MT_R, 768, tqkv_w + wqkv, 2304,
                                                         tqkv_b + (size_t)l * 2304, MODE_BF16, QKVb, nullptr, nullptr, nullptr);
        attn_t_kernel<<<1176, 256, 0, stream>>>(QKVb, Ob);
        gemm_kernel<2><<<dim3(25, 12), 256, 0, stream>>>(Ob, MT_R, 768, tproj_w + wsq, 768,
                                                         tproj_b + (size_t)l * 768, MODE_BF16, Pb, nullptr, nullptr, nullptr);
        gemm_kernel<2><<<dim3(25, 12), 256, 0, stream>>>(Pb, MT_R, 768, tfc_w + wsq, 768,
                                                         tfc_b + (size_t)l * 768, MODE_TADD, nullptr, X, nullptr, nullptr);
        // spatial
        ln_kernel<<<788, 256, 0, stream>>>(X, Ab, n1_w + l * 768, n1_b + l * 768, MS_R, 1);
        gemm_kernel<4><<<dim3(25, 18), 256, 0, stream>>>(Ab, MS_R, 768, sqkv_w + wqkv, 2304,
                                                         sqkv_b + (size_t)l * 2304, MODE_BF16, QKVb, nullptr, nullptr, nullptr);
        attn_s_kernel<<<192, 256, 0, stream>>>(QKVb, Ob);
        gemm_kernel<2><<<dim3(25, 12), 256, 0, stream>>>(Ob, MS_R, 768, sproj_w + wsq, 768,
                                                         sproj_b + (size_t)l * 768, MODE_SADD, nullptr, X, nullptr, nullptr);
        // mlp
        ln_kernel<<<785, 256, 0, stream>>>(X, Ab, n2_w + l * 768, n2_b + l * 768, MM_R, 2);
        gemm_kernel<4><<<dim3(25, 24), 256, 0, stream>>>(Ab, MM_R, 768, fc1_w + wfc, 3072,
                                                         fc1_b + (size_t)l * 3072, MODE_GELU, Hb, nullptr, nullptr, nullptr);
        gemm_kernel<2><<<dim3(25, 12), 256, 0, stream>>>(Hb, MM_R, 3072, fc2_w + wfc, 768,
                                                         fc2_b + (size_t)l * 768, MODE_MADD, nullptr, X, nullptr, nullptr);
    }

    ln_kernel<<<1, 256, 0, stream>>>(X, Ab, norm_w, norm_b, 2, 3);
    head_kernel<<<dim3(2, 4), 256, 0, stream>>>(Ab, head_w, head_b, (float*)d_out);
}